// Round 7
// baseline (203.297 us; speedup 1.0000x reference)
//
#include <hip/hip_runtime.h>

// Grid: 512x512 nodes, idx = row*512 + col. h = 1/511.
// m_in = [s_dst, deg_dst, s_src, deg_src, ea_x, ea_y] @ W1 -> tanh -> @ W2
// g(s)[n] = (1/deg_n) * sum_incoming(msg) + b2
//
// R6: pair-packed math in PACKED FP32 (v_pk_*_f32, VOP3P, VGPR-pair operands)
// forced via inline asm. Evidence R3/R4/R5: v_pk_*_f16 is HALF RATE on gfx950
// (instr-count halving + occupancy 4x both neutral); the 157.3 TF fp32 spec
// requires v_pk_fma_f32 at 2 FMA/lane/cy, so pk_f32 should be full-rate.
// tanh = Pade[5/4] + magic-reciprocal + 1 Newton, all pk f32, zero trans ops.

#define GW    512
#define GN    (GW * GW)
#define HID   64
#define SPLIT 4
#define JPT   (HID / SPLIT)    // 16 hidden units per thread
#define NUC   0.01f

typedef float        v2f __attribute__((ext_vector_type(2)));
typedef unsigned int v2u __attribute__((ext_vector_type(2)));

// Forced VOP3P packed-f32 helpers. 64-bit "v" operands print as VGPR pairs.
__device__ __forceinline__ v2f pk_fma(v2f a, v2f b, v2f c) {
    v2f d;
    asm("v_pk_fma_f32 %0, %1, %2, %3" : "=v"(d) : "v"(a), "v"(b), "v"(c));
    return d;
}
// d = (-a)*b + c  via neg modifiers (free)
__device__ __forceinline__ v2f pk_nfma(v2f a, v2f b, v2f c) {
    v2f d;
    asm("v_pk_fma_f32 %0, %1, %2, %3 neg_lo:[1,0,0] neg_hi:[1,0,0]"
        : "=v"(d) : "v"(a), "v"(b), "v"(c));
    return d;
}
__device__ __forceinline__ v2f pk_mul(v2f a, v2f b) {
    v2f d;
    asm("v_pk_mul_f32 %0, %1, %2" : "=v"(d) : "v"(a), "v"(b));
    return d;
}
__device__ __forceinline__ v2f pk_add(v2f a, v2f b) {
    v2f d;
    asm("v_pk_add_f32 %0, %1, %2" : "=v"(d) : "v"(a), "v"(b));
    return d;
}

__device__ __forceinline__ v2f vc(float x) { v2f r; r.x = x; r.y = x; return r; }
__device__ __forceinline__ v2f vp(float a, float b) { v2f r; r.x = a; r.y = b; return r; }

struct TanhC { v2f c105, c945, c15, c420, c2; };
__device__ __forceinline__ TanhC make_tc() {
    TanhC t;
    t.c105 = vc(105.f); t.c945 = vc(945.f); t.c15 = vc(15.f);
    t.c420 = vc(420.f); t.c2 = vc(2.f);
    return t;
}

// tanh(t) ~= t(945+105s+s^2)/(945+420s+15s^2), s=t^2, t=clamp(x,+-3.8).
// Reciprocal: f32 magic seed + 1 Newton (rel err ~2.5e-3). All pk f32.
__device__ __forceinline__ v2f tanh_pk(v2f x, const TanhC& tc) {
    v2f t;
    t.x = __builtin_amdgcn_fmed3f(x.x, -3.8f, 3.8f);
    t.y = __builtin_amdgcn_fmed3f(x.y, -3.8f, 3.8f);
    v2f s   = pk_mul(t, t);
    v2f num = pk_mul(t, pk_fma(s, pk_add(s, tc.c105), tc.c945));
    v2f den = pk_fma(s, pk_fma(s, tc.c15, tc.c420), tc.c945);
    v2u db  = __builtin_bit_cast(v2u, den);
    v2u mi; mi.x = 0x7EF311C3u - db.x; mi.y = 0x7EF311C3u - db.y;
    v2f r   = __builtin_bit_cast(v2f, mi);
    r = pk_mul(r, pk_nfma(den, r, tc.c2));       // Newton 1
    return pk_mul(num, r);
}

struct alignas(16) LWF {           // 64 B per hidden unit, pk-ready pairs
    v2f a0, a1, a2, a3;            // W1 rows 0..3 (duplicated into both halves)
    v2f kLR, kUD;                  // b1 + ea.W1[4:6] folded per incoming dir
    v2f c0, c1;                    // W2 row (duplicated)
};

// Swizzled store: slot = jj*SPLIT + part for original j = part*JPT + jj, so a
// wave's 4 per-quad reads are CONSECUTIVE 64B structs.
__device__ __forceinline__ void fill_lds(LWF* lw, float* sb2,
                                         const float* __restrict__ W1,
                                         const float* __restrict__ b1,
                                         const float* __restrict__ W2,
                                         const float* __restrict__ b2) {
    const int t = threadIdx.x;
    if (t < HID) {
        const float H = 1.0f / 511.0f;
        float a4 = W1[4 * HID + t], a5 = W1[5 * HID + t];
        float b  = b1[t];
        LWF w;
        w.a0 = vc(W1[0 * HID + t]); w.a1 = vc(W1[1 * HID + t]);
        w.a2 = vc(W1[2 * HID + t]); w.a3 = vc(W1[3 * HID + t]);
        w.kLR = vp(b - H * a4, b + H * a4);  // from left / from right
        w.kUD = vp(b - H * a5, b + H * a5);  // from up / from down
        w.c0 = vc(W2[2 * t + 0]);  w.c1 = vc(W2[2 * t + 1]);
        const int slot = ((t & (JPT - 1)) * SPLIT) | (t / JPT);
        lw[slot] = w;
    }
    if (t < 2) sb2[t] = b2[t];
}

// Kernel 1: grad_u, grad_v, grad_p. SoA out: g[0]=gu0 g[1]=gu1 ... g[5]=gp1
__global__ void __launch_bounds__(256) grad3_kernel(
    const float* __restrict__ fields, const float* __restrict__ degrees,
    const float* __restrict__ W1, const float* __restrict__ b1,
    const float* __restrict__ W2, const float* __restrict__ b2,
    float* __restrict__ g)
{
    __shared__ LWF lw[HID];
    __shared__ float sb2[2];
    fill_lds(lw, sb2, W1, b1, W2, b2);
    __syncthreads();

    const int gid  = blockIdx.x * 256 + threadIdx.x;
    const int idx  = gid >> 2;          // node (4 lanes per node)
    const int part = gid & 3;           // hidden-dim slice
    const int row = idx >> 9, col = idx & (GW - 1);
    const bool vE0 = col > 0, vE1 = col < GW - 1, vE2 = row > 0, vE3 = row < GW - 1;
    int nb[4];
    nb[0] = vE0 ? idx - 1  : idx;
    nb[1] = vE1 ? idx + 1  : idx;
    nb[2] = vE2 ? idx - GW : idx;
    nb[3] = vE3 ? idx + GW : idx;

    const TanhC tc = make_tc();

    v2f s0p[3];
    #pragma unroll
    for (int f = 0; f < 3; ++f) s0p[f] = vc(fields[3 * idx + f]);
    v2f sN2[2][3];                      // [pair LR/UD][field]
    #pragma unroll
    for (int f = 0; f < 3; ++f) {
        sN2[0][f] = vp(fields[3 * nb[0] + f], fields[3 * nb[1] + f]);
        sN2[1][f] = vp(fields[3 * nb[2] + f], fields[3 * nb[3] + f]);
    }
    v2f dnbLR = vp(degrees[nb[0]], degrees[nb[1]]);
    v2f dnbUD = vp(degrees[nb[2]], degrees[nb[3]]);
    const float dN = degrees[idx];
    const v2f dN2 = vc(dN);

    v2f acc[2][3][2];                   // [pair][field][W2 comp]
    #pragma unroll
    for (int dp = 0; dp < 2; ++dp)
        #pragma unroll
        for (int f = 0; f < 3; ++f) { acc[dp][f][0] = vc(0.f); acc[dp][f][1] = vc(0.f); }

    const LWF* lwp = lw + part;         // quad-consecutive slots
    #pragma unroll 2
    for (int jj = 0; jj < JPT; ++jj) {
        LWF w = lwp[jj * SPLIT];
        v2f dn1 = pk_mul(dN2, w.a1);
        v2f hb[2];
        hb[0] = pk_fma(dnbLR, w.a3, pk_add(w.kLR, dn1));
        hb[1] = pk_fma(dnbUD, w.a3, pk_add(w.kUD, dn1));
        #pragma unroll
        for (int f = 0; f < 3; ++f) {
            #pragma unroll
            for (int dp = 0; dp < 2; ++dp) {
                v2f hh = pk_fma(sN2[dp][f], w.a2, pk_fma(s0p[f], w.a0, hb[dp]));
                v2f th = tanh_pk(hh, tc);
                acc[dp][f][0] = pk_fma(th, w.c0, acc[dp][f][0]);
                acc[dp][f][1] = pk_fma(th, w.c1, acc[dp][f][1]);
            }
        }
    }

    const float rd = __builtin_amdgcn_rcpf(dN);
    #pragma unroll
    for (int f = 0; f < 3; ++f) {
        #pragma unroll
        for (int c = 0; c < 2; ++c) {
            float s = 0.f;
            s += vE0 ? acc[0][f][c].x : 0.f;
            s += vE1 ? acc[0][f][c].y : 0.f;
            s += vE2 ? acc[1][f][c].x : 0.f;
            s += vE3 ? acc[1][f][c].y : 0.f;
            s += __shfl_xor(s, 1);
            s += __shfl_xor(s, 2);
            if (part == 0)
                g[(2 * f + c) * GN + idx] = __builtin_fmaf(s, rd, sb2[c]);
        }
    }
}

// Kernel 2: second-order g on gu0,gu1,gv0,gv1 (needed comps 0,1,0,1) + combine.
__global__ void __launch_bounds__(256) final_kernel(
    const float* __restrict__ fields, const float* __restrict__ degrees,
    const float* __restrict__ W1, const float* __restrict__ b1,
    const float* __restrict__ W2, const float* __restrict__ b2,
    const float* __restrict__ g, float* __restrict__ out)
{
    __shared__ LWF lw[HID];
    __shared__ float sb2[2];
    fill_lds(lw, sb2, W1, b1, W2, b2);
    __syncthreads();

    const int gid  = blockIdx.x * 256 + threadIdx.x;
    const int idx  = gid >> 2;
    const int part = gid & 3;
    const int row = idx >> 9, col = idx & (GW - 1);
    const bool vE0 = col > 0, vE1 = col < GW - 1, vE2 = row > 0, vE3 = row < GW - 1;
    int nb[4];
    nb[0] = vE0 ? idx - 1  : idx;
    nb[1] = vE1 ? idx + 1  : idx;
    nb[2] = vE2 ? idx - GW : idx;
    nb[3] = vE3 ? idx + GW : idx;

    const TanhC tc = make_tc();

    float s0[4];
    #pragma unroll
    for (int f = 0; f < 4; ++f) s0[f] = g[f * GN + idx];
    v2f s0p[4];
    #pragma unroll
    for (int f = 0; f < 4; ++f) s0p[f] = vc(s0[f]);
    v2f sN2[2][4];
    #pragma unroll
    for (int f = 0; f < 4; ++f) {
        sN2[0][f] = vp(g[f * GN + nb[0]], g[f * GN + nb[1]]);
        sN2[1][f] = vp(g[f * GN + nb[2]], g[f * GN + nb[3]]);
    }
    v2f dnbLR = vp(degrees[nb[0]], degrees[nb[1]]);
    v2f dnbUD = vp(degrees[nb[2]], degrees[nb[3]]);
    const float dN = degrees[idx];
    const v2f dN2 = vc(dN);

    v2f acc[2][4];                      // [pair][field]
    #pragma unroll
    for (int dp = 0; dp < 2; ++dp)
        #pragma unroll
        for (int f = 0; f < 4; ++f) acc[dp][f] = vc(0.f);

    const LWF* lwp = lw + part;
    #pragma unroll 2
    for (int jj = 0; jj < JPT; ++jj) {
        LWF w = lwp[jj * SPLIT];
        v2f dn1 = pk_mul(dN2, w.a1);
        v2f hb[2];
        hb[0] = pk_fma(dnbLR, w.a3, pk_add(w.kLR, dn1));
        hb[1] = pk_fma(dnbUD, w.a3, pk_add(w.kUD, dn1));
        #pragma unroll
        for (int f = 0; f < 4; ++f) {
            v2f cc = (f & 1) ? w.c1 : w.c0;   // needed comp: 0,1,0,1
            #pragma unroll
            for (int dp = 0; dp < 2; ++dp) {
                v2f hh = pk_fma(sN2[dp][f], w.a2, pk_fma(s0p[f], w.a0, hb[dp]));
                v2f th = tanh_pk(hh, tc);
                acc[dp][f] = pk_fma(th, cc, acc[dp][f]);
            }
        }
    }

    const float rd = __builtin_amdgcn_rcpf(dN);
    float r[4];
    #pragma unroll
    for (int f = 0; f < 4; ++f) {
        float s = 0.f;
        s += vE0 ? acc[0][f].x : 0.f;
        s += vE1 ? acc[0][f].y : 0.f;
        s += vE2 ? acc[1][f].x : 0.f;
        s += vE3 ? acc[1][f].y : 0.f;
        s += __shfl_xor(s, 1);
        s += __shfl_xor(s, 2);
        r[f] = __builtin_fmaf(s, rd, sb2[f & 1]);
    }

    if (part == 0) {
        const float lap_u = r[0] + r[1];
        const float lap_v = r[2] + r[3];
        const float u = fields[3 * idx + 0], v = fields[3 * idx + 1];
        const float gu0 = s0[0], gu1 = s0[1], gv0 = s0[2], gv1 = s0[3];
        const float gp0 = g[4 * GN + idx], gp1 = g[5 * GN + idx];
        out[3 * idx + 0] = gu0 + gv1;
        out[3 * idx + 1] = u * gu0 + v * gu1 + gp0 - NUC * lap_u;
        out[3 * idx + 2] = u * gv0 + v * gv1 + gp1 - NUC * lap_v;
    }
}

extern "C" void kernel_launch(void* const* d_in, const int* in_sizes, int n_in,
                              void* d_out, int out_size, void* d_ws, size_t ws_size,
                              hipStream_t stream) {
    const float* fields  = (const float*)d_in[0];
    const float* degrees = (const float*)d_in[1];
    const float* W1 = (const float*)d_in[3];
    const float* b1 = (const float*)d_in[4];
    const float* W2 = (const float*)d_in[5];
    const float* b2 = (const float*)d_in[6];
    float* g   = (float*)d_ws;           // 6 * GN floats = 6.3 MB scratch
    float* out = (float*)d_out;

    const int blocks = (GN * SPLIT) / 256;   // 4096
    grad3_kernel<<<blocks, 256, 0, stream>>>(fields, degrees, W1, b1, W2, b2, g);
    final_kernel<<<blocks, 256, 0, stream>>>(fields, degrees, W1, b1, W2, b2, g, out);
}